// Round 11
// baseline (231.952 us; speedup 1.0000x reference)
//
#include <hip/hip_runtime.h>

typedef short s16;
typedef unsigned short us16;
typedef __attribute__((ext_vector_type(8))) short s16x8;
typedef __attribute__((ext_vector_type(8))) unsigned short u16x8;
typedef __attribute__((ext_vector_type(4))) float f32x4;

#define TOKENS 2048
#define INF    4096   // n_codes * 8
#define OUTF   4096   // m
#define GK     4096

// float -> bf16 round-to-nearest-even
__device__ __forceinline__ us16 f2bf(float f) {
    union { float f; unsigned u; } v; v.f = f;
    unsigned r = v.u + 0x7FFFu + ((v.u >> 16) & 1u);
    return (us16)(r >> 16);
}
__device__ __forceinline__ float bf2f(us16 u) {
    unsigned x = ((unsigned)u) << 16;
    float f; __builtin_memcpy(&f, &x, 4);
    return f;
}

// ---------------------------------------------------------------------------
// FWHT-16 fully in registers
// ---------------------------------------------------------------------------
__device__ __forceinline__ void fwht16(float v[16]) {
#pragma unroll
    for (int s = 1; s < 16; s <<= 1)
#pragma unroll
        for (int j = 0; j < 16; ++j)
            if (!(j & s)) {
                float a = v[j], b = v[j + s];
                v[j]     = a + b;
                v[j + s] = a - b;
            }
}

// ---------------------------------------------------------------------------
// Kernel 1 (merged): blocks [0,2048): y = bf16(FWHT(x*SU)/64)  (radix-16^3)
//   blocks [2048,2304): build decompress LUT — lut[code][0..7] bf16 for ALL
//   65536 possible 16-bit codes (1 MB, L2-resident). W is never materialized.
// ---------------------------------------------------------------------------
__global__ __launch_bounds__(256) void k_pre(const float* __restrict__ X,
                                             const float* __restrict__ SU,
                                             us16* __restrict__ Y,
                                             const void* __restrict__ gridraw,
                                             us16* __restrict__ lut) {
    __shared__ float s[4096 + 256];
    const int tid = threadIdx.x;

    if (blockIdx.x < TOKENS) {
        const int row = blockIdx.x;
        const int hi = tid >> 4, lo = tid & 15;
        float v[16];
        const float* xr = X + (size_t)row * INF;

#pragma unroll
        for (int j = 0; j < 16; ++j) v[j] = xr[j * 256 + tid] * SU[j * 256 + tid];
        fwht16(v);
#pragma unroll
        for (int j = 0; j < 16; ++j) s[272 * j + 17 * hi + lo] = v[j];
        __syncthreads();

#pragma unroll
        for (int j = 0; j < 16; ++j) v[j] = s[272 * hi + 17 * j + lo];
        fwht16(v);
#pragma unroll
        for (int j = 0; j < 16; ++j) s[272 * hi + 17 * j + lo] = v[j];
        __syncthreads();

        const int base = 272 * hi + 17 * lo;
#pragma unroll
        for (int j = 0; j < 16; ++j) v[j] = s[base + j];
        fwht16(v);

        s16x8 o0, o1;
#pragma unroll
        for (int j = 0; j < 8; ++j) {
            o0[j] = (s16)f2bf(v[j]     * 0.015625f);
            o1[j] = (s16)f2bf(v[j + 8] * 0.015625f);
        }
        s16x8* out = reinterpret_cast<s16x8*>(Y + (size_t)row * INF + tid * 16);
        out[0] = o0; out[1] = o1;
    } else {
        // -------- LUT build: code = (blockIdx.x-2048)*256 + tid --------
        float (*gT)[256] = (float(*)[256])s;
        int* gOdd = (int*)(s + 2048);

        const unsigned short* gu = (const unsigned short*)gridraw;
        const float*          gf = (const float*)gridraw;
        const unsigned short  p0 = gu[0];

        float sum = 0.f;
#pragma unroll
        for (int j = 0; j < 8; ++j) {
            float v;
            if (p0 == 0x3800) {                       // float16
                unsigned short u = gu[tid * 8 + j];
                _Float16 hv; __builtin_memcpy(&hv, &u, 2);
                v = (float)hv;
            } else if (p0 == 0x3F00) {                // bfloat16
                v = bf2f(gu[tid * 8 + j]);
            } else {                                  // float32
                v = gf[tid * 8 + j];
            }
            gT[j][tid] = v;
            sum += v;
        }
        gOdd[tid] = ((int)(sum + 0.5f)) & 1;
        __syncthreads();

        const int q = (blockIdx.x - TOKENS) * 256 + tid;   // 0..65535
        const int absIdx   = (q >> 8) & 255;
        const int signBits = (q >> 1) & 127;
        const float shift  = (q & 1) ? 0.25f : -0.25f;
        const int neg0 = (__popc(signBits) ^ gOdd[absIdx]) & 1;

        s16x8 o;
        o[0] = (s16)f2bf(gT[0][absIdx] * (1.0f - 2.0f * (float)neg0) + shift);
#pragma unroll
        for (int i = 1; i < 8; ++i) {
            float sg = 1.0f - 2.0f * (float)((signBits >> (i - 1)) & 1);
            o[i] = (s16)f2bf(gT[i][absIdx] * sg + shift);
        }
        *reinterpret_cast<s16x8*>(lut + (size_t)q * 8) = o;
    }
}

// ---------------------------------------------------------------------------
// Kernel 2: GEMM  z[t][j] = sum_k y[t][k] * W[j][k], W decompressed ON THE FLY
// from Qidxs via the 1MB L2-resident LUT. 128x256 tile, BK=32, 8 waves
// (2Mx4N), wave tile 64x64, KSPLIT=1 (grid 256 = 1/CU).
// A: gload_lds(16B), linear LDS dest, inverse-swizzled global source.
// B: per thread 2 codes -> 2x16B lut gathers -> 2x swizzled ds_write_b128;
//    Q prefetched one tile ahead (qn register) so Q->lut->write spans tiles.
// Single __syncthreads per K-tile; STAGE(t+2) after barrier. Swizzle:
// chunk c (0..3) ^= (row>>1)&3 on both write and read sides.
// ---------------------------------------------------------------------------
#define BM 128
#define BN 256
#define BK 32

__global__ __launch_bounds__(512, 1) void k_gemm(const us16* __restrict__ A,
                                                 const int* __restrict__ Q,
                                                 const us16* __restrict__ lut,
                                                 us16* __restrict__ Z) {
    __shared__ __align__(16) us16 lA[2][BM * BK];   // 2 x 8 KiB
    __shared__ __align__(16) us16 lB[2][BN * BK];   // 2 x 16 KiB
    const int tid  = threadIdx.x;
    const int lane = tid & 63;
    const int w    = tid >> 6;          // 0..7
    const int wr   = w >> 2, wc = w & 3;
    const int laneRow = lane & 15, laneK = lane >> 4;   // laneK 0..3

    // bijective XCD swizzle over nwg = 256
    const int bid = blockIdx.x;
    const int swz = (bid & 7) * 32 + (bid >> 3);
    const int mT  = swz >> 4;           // 0..15
    const int nT  = swz & 15;           // 0..15
    const int KT  = GK / BK;            // 128

    // ---- A staging: 512 chunks of 16B (1/thread) ----
    size_t aOff;
    {
        int rr = tid >> 2, cc = tid & 3;
        int sc = cc ^ ((rr >> 1) & 3);
        aOff = (size_t)(mT * BM + rr) * GK + sc * 8;
    }
    const int ldsOffA = (w * 64) * 8;       // wave-uniform halfs

    // ---- B staging: thread -> row rr = tid>>1, code pair (tid&1)*2 ----
    const int rrB  = tid >> 1;
    const int half = tid & 1;
    const int bswz = (rrB >> 1) & 3;
    const size_t qBase = (size_t)(nT * BN + rrB) * 512 + 2 * half;  // + t*4
    const int off0 = rrB * 32 + ((2 * half)     ^ bswz) * 8;  // halfs
    const int off1 = rrB * 32 + ((2 * half + 1) ^ bswz) * 8;

    // fragment read bases (halfs): row r -> r*32 + (laneK ^ ((r>>1)&3))*8
    int aB[4], aX[4], bB[4], bX[4];
#pragma unroll
    for (int mi = 0; mi < 4; ++mi) {
        int r = wr * 64 + mi * 16 + laneRow;
        aB[mi] = r * 32; aX[mi] = (r >> 1) & 3;
    }
#pragma unroll
    for (int nj = 0; nj < 4; ++nj) {
        int r = wc * 64 + nj * 16 + laneRow;
        bB[nj] = r * 32; bX[nj] = (r >> 1) & 3;
    }

    f32x4 acc[4][4] = {};   // [mi][nj]

#define STAGE_A(t, buf) \
    __builtin_amdgcn_global_load_lds( \
        (const __attribute__((address_space(1))) void*)(A + aOff + (size_t)(t) * BK), \
        (__attribute__((address_space(3))) void*)(&lA[buf][0] + ldsOffA), 16, 0, 0)

#define STAGE_B_FROM(qv, buf) do { \
    s16x8 w0 = *reinterpret_cast<const s16x8*>(lut + (size_t)((qv).x & 0xffff) * 8); \
    s16x8 w1 = *reinterpret_cast<const s16x8*>(lut + (size_t)((qv).y & 0xffff) * 8); \
    *reinterpret_cast<s16x8*>(&lB[buf][0] + off0) = w0; \
    *reinterpret_cast<s16x8*>(&lB[buf][0] + off1) = w1; \
    } while (0)

    // prologue: stage tiles 0 and 1; preload q for tile 2
    {
        int2 q0 = *reinterpret_cast<const int2*>(Q + qBase + 0 * 4);
        int2 q1 = *reinterpret_cast<const int2*>(Q + qBase + 1 * 4);
        STAGE_A(0, 0);
        STAGE_A(1, 1);
        STAGE_B_FROM(q0, 0);
        STAGE_B_FROM(q1, 1);
    }
    int2 qn = *reinterpret_cast<const int2*>(Q + qBase + 2 * 4);
    __syncthreads();

    int cur = 0;
    for (int t = 0; t < KT; ++t) {
        const us16* pA = &lA[cur][0];
        const us16* pB = &lB[cur][0];

        s16x8 af[4], bf[4];
#pragma unroll
        for (int mi = 0; mi < 4; ++mi)
            af[mi] = *reinterpret_cast<const s16x8*>(pA + aB[mi] + (laneK ^ aX[mi]) * 8);
#pragma unroll
        for (int nj = 0; nj < 4; ++nj)
            bf[nj] = *reinterpret_cast<const s16x8*>(pB + bB[nj] + (laneK ^ bX[nj]) * 8);

#pragma unroll
        for (int mi = 0; mi < 4; ++mi)
#pragma unroll
            for (int nj = 0; nj < 4; ++nj)
                acc[mi][nj] = __builtin_amdgcn_mfma_f32_16x16x32_bf16(
                    af[mi], bf[nj], acc[mi][nj], 0, 0, 0);

        // one barrier per K-tile: drains old stage loads/writes, fences reads
        __syncthreads();

        if (t + 2 < KT) {
            STAGE_A(t + 2, cur);
            STAGE_B_FROM(qn, cur);       // q was prefetched one tile ago
            int nt3 = (t + 3 < KT) ? (t + 3) : (KT - 1);
            qn = *reinterpret_cast<const int2*>(Q + qBase + (size_t)nt3 * 4);
        }
        cur ^= 1;
    }
#undef STAGE_A
#undef STAGE_B_FROM

    // C/D layout: col = lane&15, row = (lane>>4)*4 + reg
    const int colB = nT * BN + wc * 64 + laneRow;
    const int rowB = mT * BM + wr * 64 + laneK * 4;
#pragma unroll
    for (int mi = 0; mi < 4; ++mi)
#pragma unroll
        for (int nj = 0; nj < 4; ++nj)
#pragma unroll
            for (int rg = 0; rg < 4; ++rg)
                Z[(size_t)(rowB + mi * 16 + rg) * OUTF + colB + nj * 16]
                    = f2bf(acc[mi][nj][rg]);
}

// ---------------------------------------------------------------------------
// Kernel 3: OUT = FWHT(bf16 Z) * (Wscale/64) * SV
// Digit-reordered radix-16^3: low digit first on contiguous 32B loads.
// ---------------------------------------------------------------------------
__global__ __launch_bounds__(256) void k_out(const us16* __restrict__ Z,
                                             float* __restrict__ OUT,
                                             const float* __restrict__ SV,
                                             const float* __restrict__ wscale) {
    __shared__ float s[4096 + 272];
    const int row = blockIdx.x, t = threadIdx.x;
    float v[16];
    const us16* zr = Z + (size_t)row * OUTF;

    // pass C (digit c): elements e = t*16 + j, contiguous 32B
    {
        u16x8 a0 = reinterpret_cast<const u16x8*>(zr + t * 16)[0];
        u16x8 a1 = reinterpret_cast<const u16x8*>(zr + t * 16)[1];
#pragma unroll
        for (int j = 0; j < 8; ++j) {
            v[j]     = bf2f(a0[j]);
            v[j + 8] = bf2f(a1[j]);
        }
    }
    fwht16(v);
#pragma unroll
    for (int j = 0; j < 16; ++j) s[17 * t + j] = v[j];
    __syncthreads();

    // pass B (digit b): phys = 272*a0 + 17*j + c0
    const int pa = 272 * (t >> 4) + (t & 15);
#pragma unroll
    for (int j = 0; j < 16; ++j) v[j] = s[pa + 17 * j];
    fwht16(v);
#pragma unroll
    for (int j = 0; j < 16; ++j) s[pa + 17 * j] = v[j];
    __syncthreads();

    // pass A (digit a): phys = 272*j + 17*b0 + c0
    const int pb = 17 * (t >> 4) + (t & 15);
#pragma unroll
    for (int j = 0; j < 16; ++j) v[j] = s[272 * j + pb];
    fwht16(v);

    const float sc = wscale[0] * 0.015625f;
    float* orow = OUT + (size_t)row * OUTF;
#pragma unroll
    for (int j = 0; j < 16; ++j)
        orow[j * 256 + t] = v[j] * sc * SV[j * 256 + t];
}

// ---------------------------------------------------------------------------
extern "C" void kernel_launch(void* const* d_in, const int* in_sizes, int n_in,
                              void* d_out, int out_size, void* d_ws, size_t ws_size,
                              hipStream_t stream) {
    const float* input  = (const float*)d_in[0];   // (2048, 4096) f32
    const int*   Qidxs  = (const int*)d_in[1];     // (4096, 512) i32
    const float* SU     = (const float*)d_in[2];   // (4096,) f32
    const float* SV     = (const float*)d_in[3];   // (4096,) f32
    const float* Wscale = (const float*)d_in[4];   // (1,) f32
    const void*  grid   = (const void*)d_in[9];    // (256, 8) grid_abs (dtype-probed)

    us16* Y   = (us16*)d_ws;                                       // 16 MB
    us16* Z   = (us16*)((char*)d_ws + (size_t)16 * 1024 * 1024);   // 16 MB
    us16* lut = (us16*)((char*)d_ws + (size_t)32 * 1024 * 1024);   // 1 MB

    hipLaunchKernelGGL(k_pre, dim3(TOKENS + 256), dim3(256), 0, stream,
                       input, SU, Y, grid, lut);
    hipLaunchKernelGGL(k_gemm, dim3(256), dim3(512), 0, stream,
                       Y, Qidxs, lut, Z);
    hipLaunchKernelGGL(k_out, dim3(TOKENS), dim3(256), 0, stream,
                       Z, (float*)d_out, SV, Wscale);
}

// Round 12
// 153.045 us; speedup vs baseline: 1.5156x; 1.5156x over previous
//
#include <hip/hip_runtime.h>

typedef short s16;
typedef unsigned short us16;
typedef __attribute__((ext_vector_type(8))) short s16x8;
typedef __attribute__((ext_vector_type(8))) unsigned short u16x8;
typedef __attribute__((ext_vector_type(4))) float f32x4;

#define TOKENS 2048
#define INF    4096   // n_codes * 8
#define OUTF   4096   // m
#define GK     4096

// float -> bf16 round-to-nearest-even
__device__ __forceinline__ us16 f2bf(float f) {
    union { float f; unsigned u; } v; v.f = f;
    unsigned r = v.u + 0x7FFFu + ((v.u >> 16) & 1u);
    return (us16)(r >> 16);
}
__device__ __forceinline__ float bf2f(us16 u) {
    unsigned x = ((unsigned)u) << 16;
    float f; __builtin_memcpy(&f, &x, 4);
    return f;
}

// ---------------------------------------------------------------------------
// FWHT-16 fully in registers
// ---------------------------------------------------------------------------
__device__ __forceinline__ void fwht16(float v[16]) {
#pragma unroll
    for (int s = 1; s < 16; s <<= 1)
#pragma unroll
        for (int j = 0; j < 16; ++j)
            if (!(j & s)) {
                float a = v[j], b = v[j + s];
                v[j]     = a + b;
                v[j + s] = a - b;
            }
}

// ---------------------------------------------------------------------------
// Kernel 1 (merged): blocks [0,2048): y = bf16(FWHT(x*SU)/64)  (radix-16^3)
//                    blocks [2048, 10240): decompress E8P -> W (bf16)
// ---------------------------------------------------------------------------
__global__ __launch_bounds__(256) void k_pre(const float* __restrict__ X,
                                             const float* __restrict__ SU,
                                             us16* __restrict__ Y,
                                             const int* __restrict__ Q,
                                             const void* __restrict__ gridraw,
                                             us16* __restrict__ W) {
    __shared__ float s[4096 + 256];
    const int tid = threadIdx.x;

    if (blockIdx.x < TOKENS) {
        const int row = blockIdx.x;
        const int hi = tid >> 4, lo = tid & 15;
        float v[16];
        const float* xr = X + (size_t)row * INF;

#pragma unroll
        for (int j = 0; j < 16; ++j) v[j] = xr[j * 256 + tid] * SU[j * 256 + tid];
        fwht16(v);
#pragma unroll
        for (int j = 0; j < 16; ++j) s[272 * j + 17 * hi + lo] = v[j];
        __syncthreads();

#pragma unroll
        for (int j = 0; j < 16; ++j) v[j] = s[272 * hi + 17 * j + lo];
        fwht16(v);
#pragma unroll
        for (int j = 0; j < 16; ++j) s[272 * hi + 17 * j + lo] = v[j];
        __syncthreads();

        const int base = 272 * hi + 17 * lo;
#pragma unroll
        for (int j = 0; j < 16; ++j) v[j] = s[base + j];
        fwht16(v);

        s16x8 o0, o1;
#pragma unroll
        for (int j = 0; j < 8; ++j) {
            o0[j] = (s16)f2bf(v[j]     * 0.015625f);
            o1[j] = (s16)f2bf(v[j + 8] * 0.015625f);
        }
        s16x8* out = reinterpret_cast<s16x8*>(Y + (size_t)row * INF + tid * 16);
        out[0] = o0; out[1] = o1;
    } else {
        float (*gT)[256] = (float(*)[256])s;
        int* gOdd = (int*)(s + 2048);

        const unsigned short* gu = (const unsigned short*)gridraw;
        const float*          gf = (const float*)gridraw;
        const unsigned short  p0 = gu[0];

        float sum = 0.f;
#pragma unroll
        for (int j = 0; j < 8; ++j) {
            float v;
            if (p0 == 0x3800) {                       // float16
                unsigned short u = gu[tid * 8 + j];
                _Float16 hv; __builtin_memcpy(&hv, &u, 2);
                v = (float)hv;
            } else if (p0 == 0x3F00) {                // bfloat16
                v = bf2f(gu[tid * 8 + j]);
            } else {                                  // float32
                v = gf[tid * 8 + j];
            }
            gT[j][tid] = v;
            sum += v;
        }
        gOdd[tid] = ((int)(sum + 0.5f)) & 1;
        __syncthreads();

        const int code = (blockIdx.x - TOKENS) * 256 + tid;
        const int q        = Q[code];
        const int absIdx   = (q >> 8) & 255;
        const int signBits = (q >> 1) & 127;
        const float shift  = (q & 1) ? 0.25f : -0.25f;
        const int neg0 = (__popc(signBits) ^ gOdd[absIdx]) & 1;

        s16x8 o;
        o[0] = (s16)f2bf(gT[0][absIdx] * (1.0f - 2.0f * (float)neg0) + shift);
#pragma unroll
        for (int i = 1; i < 8; ++i) {
            float sg = 1.0f - 2.0f * (float)((signBits >> (i - 1)) & 1);
            o[i] = (s16)f2bf(gT[i][absIdx] * sg + shift);
        }
        *reinterpret_cast<s16x8*>(W + (size_t)code * 8) = o;
    }
}

// ---------------------------------------------------------------------------
// Kernel 2: GEMM  z[t][j] = sum_k y[t][k] * W[j][k]  (NT, K-major, bf16)
// 128x256 tile, BK=32, 8 waves (2Mx4N), wave tile 64x64, KSPLIT=1
// (grid 256; occupancy proven irrelevant r10). Output bf16 Z (one rounding).
// Single __syncthreads per K-tile (r6 structure), STAGE(t+2) after barrier.
// Swizzle: 16B chunk c (0..3) ^= (row>>1)&3 on both write and read sides.
// gload_lds(16B): linear LDS dest, inverse-swizzled global source.
// ---------------------------------------------------------------------------
#define BM 128
#define BN 256
#define BK 32

__global__ __launch_bounds__(512, 1) void k_gemm(const us16* __restrict__ A,
                                                 const us16* __restrict__ B,
                                                 us16* __restrict__ Z) {
    __shared__ __align__(16) us16 lA[2][BM * BK];   // 2 x 8 KiB
    __shared__ __align__(16) us16 lB[2][BN * BK];   // 2 x 16 KiB
    const int tid  = threadIdx.x;
    const int lane = tid & 63;
    const int w    = tid >> 6;          // 0..7
    const int wr   = w >> 2, wc = w & 3;
    const int laneRow = lane & 15, laneK = lane >> 4;   // laneK 0..3

    // bijective XCD swizzle over nwg = 256 (multiple of 8)
    const int bid = blockIdx.x;
    const int swz = (bid & 7) * 32 + (bid >> 3);
    const int mT  = swz >> 4;           // 0..15
    const int nT  = swz & 15;           // 0..15
    const int KT  = GK / BK;            // 128

    // staging: A 512 chunks (1/thread), B 1024 chunks (2/thread), 16B each
    size_t aOff;
    {
        int rr = tid >> 2, cc = tid & 3;
        int sc = cc ^ ((rr >> 1) & 3);
        aOff = (size_t)(mT * BM + rr) * GK + sc * 8;
    }
    const int ldsOffA = (w * 64) * 8;       // wave-uniform halfs
    size_t bOff[2];
    int ldsOffB[2];
#pragma unroll
    for (int j = 0; j < 2; ++j) {
        int ch = j * 512 + tid;
        int rr = ch >> 2, cc = ch & 3;
        int sc = cc ^ ((rr >> 1) & 3);
        bOff[j] = (size_t)(nT * BN + rr) * GK + sc * 8;
        ldsOffB[j] = ((j * 512 + w * 64)) * 8;
    }

    // fragment read bases (halfs): row r -> r*32 + (laneK ^ ((r>>1)&3))*8
    int aB[4], aX[4], bB[4], bX[4];
#pragma unroll
    for (int mi = 0; mi < 4; ++mi) {
        int r = wr * 64 + mi * 16 + laneRow;
        aB[mi] = r * 32; aX[mi] = (r >> 1) & 3;
    }
#pragma unroll
    for (int nj = 0; nj < 4; ++nj) {
        int r = wc * 64 + nj * 16 + laneRow;
        bB[nj] = r * 32; bX[nj] = (r >> 1) & 3;
    }

    f32x4 acc[4][4] = {};   // [mi][nj]

#define STAGE(t, buf) do { const size_t _ko = (size_t)(t) * BK; \
    __builtin_amdgcn_global_load_lds( \
        (const __attribute__((address_space(1))) void*)(A + aOff + _ko), \
        (__attribute__((address_space(3))) void*)(&lA[buf][0] + ldsOffA), 16, 0, 0); \
    _Pragma("unroll") \
    for (int j = 0; j < 2; ++j) \
        __builtin_amdgcn_global_load_lds( \
            (const __attribute__((address_space(1))) void*)(B + bOff[j] + _ko), \
            (__attribute__((address_space(3))) void*)(&lB[buf][0] + ldsOffB[j]), 16, 0, 0); \
    } while (0)

    // prologue: stage tiles 0 and 1
    STAGE(0, 0);
    STAGE(1, 1);
    __syncthreads();

    int cur = 0;
    for (int t = 0; t < KT; ++t) {
        const us16* pA = &lA[cur][0];
        const us16* pB = &lB[cur][0];

        s16x8 af[4], bf[4];
#pragma unroll
        for (int mi = 0; mi < 4; ++mi)
            af[mi] = *reinterpret_cast<const s16x8*>(pA + aB[mi] + (laneK ^ aX[mi]) * 8);
#pragma unroll
        for (int nj = 0; nj < 4; ++nj)
            bf[nj] = *reinterpret_cast<const s16x8*>(pB + bB[nj] + (laneK ^ bX[nj]) * 8);

#pragma unroll
        for (int mi = 0; mi < 4; ++mi)
#pragma unroll
            for (int nj = 0; nj < 4; ++nj)
                acc[mi][nj] = __builtin_amdgcn_mfma_f32_16x16x32_bf16(
                    af[mi], bf[nj], acc[mi][nj], 0, 0, 0);

        // one barrier per K-tile: implicit vmcnt(0) drains tile-(t+1) stages
        // (issued a full K-tile ago) and fences all waves' reads of buf[cur].
        __syncthreads();

        if (t + 2 < KT) { STAGE(t + 2, cur); }
        cur ^= 1;
    }
#undef STAGE

    // C/D layout: col = lane&15, row = (lane>>4)*4 + reg
    const int colB = nT * BN + wc * 64 + laneRow;
    const int rowB = mT * BM + wr * 64 + laneK * 4;
#pragma unroll
    for (int mi = 0; mi < 4; ++mi)
#pragma unroll
        for (int nj = 0; nj < 4; ++nj)
#pragma unroll
            for (int rg = 0; rg < 4; ++rg)
                Z[(size_t)(rowB + mi * 16 + rg) * OUTF + colB + nj * 16]
                    = f2bf(acc[mi][nj][rg]);
}

// ---------------------------------------------------------------------------
// Kernel 3: OUT = FWHT(bf16 Z) * (Wscale/64) * SV
// Digit-reordered radix-16^3: low digit first on contiguous 32B loads,
// then mid/high digits via padded LDS phys(e)=e+(e>>4).
// ---------------------------------------------------------------------------
__global__ __launch_bounds__(256) void k_out(const us16* __restrict__ Z,
                                             float* __restrict__ OUT,
                                             const float* __restrict__ SV,
                                             const float* __restrict__ wscale) {
    __shared__ float s[4096 + 272];
    const int row = blockIdx.x, t = threadIdx.x;
    float v[16];
    const us16* zr = Z + (size_t)row * OUTF;

    // pass C (digit c): elements e = t*16 + j, contiguous 32B
    {
        u16x8 a0 = reinterpret_cast<const u16x8*>(zr + t * 16)[0];
        u16x8 a1 = reinterpret_cast<const u16x8*>(zr + t * 16)[1];
#pragma unroll
        for (int j = 0; j < 8; ++j) {
            v[j]     = bf2f(a0[j]);
            v[j + 8] = bf2f(a1[j]);
        }
    }
    fwht16(v);
#pragma unroll
    for (int j = 0; j < 16; ++j) s[17 * t + j] = v[j];
    __syncthreads();

    // pass B (digit b): phys = 272*a0 + 17*j + c0
    const int pa = 272 * (t >> 4) + (t & 15);
#pragma unroll
    for (int j = 0; j < 16; ++j) v[j] = s[pa + 17 * j];
    fwht16(v);
#pragma unroll
    for (int j = 0; j < 16; ++j) s[pa + 17 * j] = v[j];
    __syncthreads();

    // pass A (digit a): phys = 272*j + 17*b0 + c0
    const int pb = 17 * (t >> 4) + (t & 15);
#pragma unroll
    for (int j = 0; j < 16; ++j) v[j] = s[272 * j + pb];
    fwht16(v);

    const float sc = wscale[0] * 0.015625f;
    float* orow = OUT + (size_t)row * OUTF;
#pragma unroll
    for (int j = 0; j < 16; ++j)
        orow[j * 256 + t] = v[j] * sc * SV[j * 256 + t];
}

// ---------------------------------------------------------------------------
extern "C" void kernel_launch(void* const* d_in, const int* in_sizes, int n_in,
                              void* d_out, int out_size, void* d_ws, size_t ws_size,
                              hipStream_t stream) {
    const float* input  = (const float*)d_in[0];   // (2048, 4096) f32
    const int*   Qidxs  = (const int*)d_in[1];     // (4096, 512) i32
    const float* SU     = (const float*)d_in[2];   // (4096,) f32
    const float* SV     = (const float*)d_in[3];   // (4096,) f32
    const float* Wscale = (const float*)d_in[4];   // (1,) f32
    const void*  grid   = (const void*)d_in[9];    // (256, 8) grid_abs (dtype-probed)

    us16* W = (us16*)d_ws;                                       // 32 MB
    us16* Y = (us16*)((char*)d_ws + (size_t)32 * 1024 * 1024);   // 16 MB
    us16* Z = (us16*)((char*)d_ws + (size_t)48 * 1024 * 1024);   // 16 MB (bf16)

    hipLaunchKernelGGL(k_pre, dim3(TOKENS + (OUTF * 512) / 256), dim3(256), 0, stream,
                       input, SU, Y, Qidxs, grid, W);
    hipLaunchKernelGGL(k_gemm, dim3(256), dim3(512), 0, stream,
                       Y, W, Z);
    hipLaunchKernelGGL(k_out, dim3(TOKENS), dim3(256), 0, stream,
                       Z, (float*)d_out, SV, Wscale);
}

// Round 13
// 93.913 us; speedup vs baseline: 2.4699x; 1.6296x over previous
//
#include <hip/hip_runtime.h>

typedef short s16;
typedef unsigned short us16;
typedef signed char i8;
typedef __attribute__((ext_vector_type(8))) short s16x8;
typedef __attribute__((ext_vector_type(8))) unsigned short u16x8;
typedef __attribute__((ext_vector_type(8))) signed char i8x8;
typedef __attribute__((ext_vector_type(16))) signed char i8x16;
typedef __attribute__((ext_vector_type(4))) int i32x4;

#define TOKENS 2048
#define INF    4096
#define OUTF   4096
#define GK     4096

__device__ __forceinline__ us16 f2bf(float f) {
    union { float f; unsigned u; } v; v.f = f;
    unsigned r = v.u + 0x7FFFu + ((v.u >> 16) & 1u);
    return (us16)(r >> 16);
}
__device__ __forceinline__ float bf2f(us16 u) {
    unsigned x = ((unsigned)u) << 16;
    float f; __builtin_memcpy(&f, &x, 4);
    return f;
}

__device__ __forceinline__ void fwht16(float v[16]) {
#pragma unroll
    for (int s = 1; s < 16; s <<= 1)
#pragma unroll
        for (int j = 0; j < 16; ++j)
            if (!(j & s)) {
                float a = v[j], b = v[j + s];
                v[j]     = a + b;
                v[j + s] = a - b;
            }
}

// ---------------------------------------------------------------------------
// Kernel 1: blocks [0,2048): y_i8 = quant(FWHT(x*SU)), per-row scale -> ZS
//           blocks [2048,10240): decompress E8P -> W_i8 = W*4 (EXACT in i8)
// ZS[row] = vmax * (1/64) / (127*4)  so  z = acc_i32 * ZS[row]
// ---------------------------------------------------------------------------
__global__ __launch_bounds__(256) void k_pre(const float* __restrict__ X,
                                             const float* __restrict__ SU,
                                             i8* __restrict__ Y,
                                             float* __restrict__ ZS,
                                             const int* __restrict__ Q,
                                             const void* __restrict__ gridraw,
                                             i8* __restrict__ W) {
    __shared__ float s[4096 + 272];
    const int tid = threadIdx.x;

    if (blockIdx.x < TOKENS) {
        const int row = blockIdx.x;
        const int hi = tid >> 4, lo = tid & 15;
        float v[16];
        const float* xr = X + (size_t)row * INF;

#pragma unroll
        for (int j = 0; j < 16; ++j) v[j] = xr[j * 256 + tid] * SU[j * 256 + tid];
        fwht16(v);
#pragma unroll
        for (int j = 0; j < 16; ++j) s[272 * j + 17 * hi + lo] = v[j];
        __syncthreads();

#pragma unroll
        for (int j = 0; j < 16; ++j) v[j] = s[272 * hi + 17 * j + lo];
        fwht16(v);
#pragma unroll
        for (int j = 0; j < 16; ++j) s[272 * hi + 17 * j + lo] = v[j];
        __syncthreads();

        const int base = 272 * hi + 17 * lo;
#pragma unroll
        for (int j = 0; j < 16; ++j) v[j] = s[base + j];
        fwht16(v);

        // per-row absmax reduce (s[] reads are done; reuse s[0..255])
        float m16 = 0.f;
#pragma unroll
        for (int j = 0; j < 16; ++j) m16 = fmaxf(m16, fabsf(v[j]));
        __syncthreads();
        s[tid] = m16;
        __syncthreads();
#pragma unroll
        for (int off = 128; off > 0; off >>= 1) {
            if (tid < off) s[tid] = fmaxf(s[tid], s[tid + off]);
            __syncthreads();
        }
        const float vmax = fmaxf(s[0], 1e-30f);
        const float qs = 127.0f / vmax;

        i8x16 o;
#pragma unroll
        for (int j = 0; j < 16; ++j) o[j] = (i8)__float2int_rn(v[j] * qs);
        *reinterpret_cast<i8x16*>(Y + (size_t)row * INF + tid * 16) = o;
        if (tid == 0) ZS[row] = vmax * (0.015625f / 508.0f);  // /64 /(127*4)
    } else {
        float (*gT)[256] = (float(*)[256])s;
        int* gOdd = (int*)(s + 2048);

        const unsigned short* gu = (const unsigned short*)gridraw;
        const float*          gf = (const float*)gridraw;
        const unsigned short  p0 = gu[0];

        float sum = 0.f;
#pragma unroll
        for (int j = 0; j < 8; ++j) {
            float v;
            if (p0 == 0x3800) {                       // float16
                unsigned short u = gu[tid * 8 + j];
                _Float16 hv; __builtin_memcpy(&hv, &u, 2);
                v = (float)hv;
            } else if (p0 == 0x3F00) {                // bfloat16
                v = bf2f(gu[tid * 8 + j]);
            } else {                                  // float32
                v = gf[tid * 8 + j];
            }
            gT[j][tid] = v;
            sum += v;
        }
        gOdd[tid] = ((int)(sum + 0.5f)) & 1;
        __syncthreads();

        const int code = (blockIdx.x - TOKENS) * 256 + tid;
        const int q        = Q[code];
        const int absIdx   = (q >> 8) & 255;
        const int signBits = (q >> 1) & 127;
        const float shift  = (q & 1) ? 1.0f : -1.0f;        // 0.25 * 4
        const int neg0 = (__popc(signBits) ^ gOdd[absIdx]) & 1;

        i8x8 o;
        o[0] = (i8)__float2int_rn(gT[0][absIdx] * 4.0f * (1.0f - 2.0f * (float)neg0) + shift);
#pragma unroll
        for (int i = 1; i < 8; ++i) {
            float sg = 1.0f - 2.0f * (float)((signBits >> (i - 1)) & 1);
            o[i] = (i8)__float2int_rn(gT[i][absIdx] * 4.0f * sg + shift);
        }
        *reinterpret_cast<i8x8*>(W + (size_t)code * 8) = o;
    }
}

// ---------------------------------------------------------------------------
// Kernel 2: GEMM  z[t][j] = sum_k yq[t][k] * wq[j][k]  (NT, K-major, int8)
// r10-proven structure, bytes identical: 128x256 tile, BK=64 (i8) == 32 bf16
// chunks, 8 waves (2Mx4N), wave tile 64x64, KSPLIT=2 (grid 512, L2 sharing).
// mfma_i32_16x16x64_i8 (K=64/inst, 2x bf16 rate, exact i32 accum).
// Single __syncthreads per K-tile; STAGE(t+2) after barrier. 16B-chunk XOR
// swizzle c ^= (row>>1)&3 on write source and read. gload_lds(16B).
// Epilogue: z = acc * ZS[tokenrow] -> bf16 partials Z0/Z1.
// ---------------------------------------------------------------------------
#define BM 128
#define BN 256
#define BK 64   // i8 elements = 64 bytes per row = 4 x 16B chunks

__global__ __launch_bounds__(512, 4) void k_gemm(const i8* __restrict__ A,
                                                 const i8* __restrict__ B,
                                                 const float* __restrict__ ZS,
                                                 us16* __restrict__ Z0,
                                                 us16* __restrict__ Z1) {
    __shared__ __align__(16) i8 lA[2][BM * BK];   // 2 x 8 KiB
    __shared__ __align__(16) i8 lB[2][BN * BK];   // 2 x 16 KiB
    const int tid  = threadIdx.x;
    const int lane = tid & 63;
    const int w    = tid >> 6;
    const int wr   = w >> 2, wc = w & 3;
    const int laneRow = lane & 15, laneK = lane >> 4;   // laneK 0..3

    // bijective XCD swizzle over nwg = 512
    const int bid = blockIdx.x;
    const int swz = (bid & 7) * 64 + (bid >> 3);
    const int ks  = swz >> 8;           // 0..1
    const int rem = swz & 255;
    const int mT  = rem >> 4;           // 0..15
    const int nT  = rem & 15;           // 0..15
    const int KT  = (GK / 2) / BK;      // 32
    const size_t kbase = (size_t)ks * (GK / 2);

    us16* __restrict__ Z = (ks == 1) ? Z1 : Z0;

    // staging: A 512 chunks (1/thread), B 1024 chunks (2/thread), 16B each
    size_t aOff;
    {
        int rr = tid >> 2, cc = tid & 3;
        int sc = cc ^ ((rr >> 1) & 3);
        aOff = (size_t)(mT * BM + rr) * GK + kbase + sc * 16;
    }
    const int ldsOffA = w * 64 * 16;        // wave-uniform bytes
    size_t bOff[2];
    int ldsOffB[2];
#pragma unroll
    for (int j = 0; j < 2; ++j) {
        int ch = j * 512 + tid;
        int rr = ch >> 2, cc = ch & 3;
        int sc = cc ^ ((rr >> 1) & 3);
        bOff[j] = (size_t)(nT * BN + rr) * GK + kbase + sc * 16;
        ldsOffB[j] = (j * 512 + w * 64) * 16;
    }

    // fragment read bases (bytes): row r -> r*64 + (laneK ^ ((r>>1)&3))*16
    int aB[4], aX[4], bB[4], bX[4];
#pragma unroll
    for (int mi = 0; mi < 4; ++mi) {
        int r = wr * 64 + mi * 16 + laneRow;
        aB[mi] = r * 64; aX[mi] = (r >> 1) & 3;
    }
#pragma unroll
    for (int nj = 0; nj < 4; ++nj) {
        int r = wc * 64 + nj * 16 + laneRow;
        bB[nj] = r * 64; bX[nj] = (r >> 1) & 3;
    }

    i32x4 acc[4][4] = {};

#define STAGE(t, buf) do { const size_t _ko = (size_t)(t) * BK; \
    __builtin_amdgcn_global_load_lds( \
        (const __attribute__((address_space(1))) void*)(A + aOff + _ko), \
        (__attribute__((address_space(3))) void*)(&lA[buf][0] + ldsOffA), 16, 0, 0); \
    _Pragma("unroll") \
    for (int j = 0; j < 2; ++j) \
        __builtin_amdgcn_global_load_lds( \
            (const __attribute__((address_space(1))) void*)(B + bOff[j] + _ko), \
            (__attribute__((address_space(3))) void*)(&lB[buf][0] + ldsOffB[j]), 16, 0, 0); \
    } while (0)

    STAGE(0, 0);
    STAGE(1, 1);
    __syncthreads();

    int cur = 0;
    for (int t = 0; t < KT; ++t) {
        const i8* pA = &lA[cur][0];
        const i8* pB = &lB[cur][0];

        i32x4 af[4], bf[4];
#pragma unroll
        for (int mi = 0; mi < 4; ++mi)
            af[mi] = *reinterpret_cast<const i32x4*>(pA + aB[mi] + (laneK ^ aX[mi]) * 16);
#pragma unroll
        for (int nj = 0; nj < 4; ++nj)
            bf[nj] = *reinterpret_cast<const i32x4*>(pB + bB[nj] + (laneK ^ bX[nj]) * 16);

#pragma unroll
        for (int mi = 0; mi < 4; ++mi)
#pragma unroll
            for (int nj = 0; nj < 4; ++nj)
                acc[mi][nj] = __builtin_amdgcn_mfma_i32_16x16x64_i8(
                    af[mi], bf[nj], acc[mi][nj], 0, 0, 0);

        __syncthreads();
        if (t + 2 < KT) { STAGE(t + 2, cur); }
        cur ^= 1;
    }
#undef STAGE

    // C/D layout: col = lane&15, row = (lane>>4)*4 + reg
    const int colB = nT * BN + wc * 64 + laneRow;
    const int rowB = mT * BM + wr * 64 + laneK * 4;
#pragma unroll
    for (int mi = 0; mi < 4; ++mi) {
#pragma unroll
        for (int rg = 0; rg < 4; ++rg) {
            const int row = rowB + mi * 16 + rg;
            const float zs = ZS[row];
#pragma unroll
            for (int nj = 0; nj < 4; ++nj)
                Z[(size_t)row * OUTF + colB + nj * 16]
                    = f2bf((float)acc[mi][nj][rg] * zs);
        }
    }
}

// ---------------------------------------------------------------------------
// Kernel 3: OUT = FWHT(bf16 Z0 + bf16 Z1) * Wscale/64 * SV  (digit-reordered)
// ---------------------------------------------------------------------------
__global__ __launch_bounds__(256) void k_out(const us16* __restrict__ Z0,
                                             const us16* __restrict__ Z1,
                                             float* __restrict__ OUT,
                                             const float* __restrict__ SV,
                                             const float* __restrict__ wscale) {
    __shared__ float s[4096 + 272];
    const int row = blockIdx.x, t = threadIdx.x;
    float v[16];
    const us16* zr0 = Z0 + (size_t)row * OUTF;
    const us16* zr1 = Z1 + (size_t)row * OUTF;

    // pass C (low digit): contiguous 32B loads
    {
        u16x8 a0 = reinterpret_cast<const u16x8*>(zr0 + t * 16)[0];
        u16x8 a1 = reinterpret_cast<const u16x8*>(zr0 + t * 16)[1];
        u16x8 b0 = reinterpret_cast<const u16x8*>(zr1 + t * 16)[0];
        u16x8 b1 = reinterpret_cast<const u16x8*>(zr1 + t * 16)[1];
#pragma unroll
        for (int j = 0; j < 8; ++j) {
            v[j]     = bf2f(a0[j]) + bf2f(b0[j]);
            v[j + 8] = bf2f(a1[j]) + bf2f(b1[j]);
        }
    }
    fwht16(v);
#pragma unroll
    for (int j = 0; j < 16; ++j) s[17 * t + j] = v[j];
    __syncthreads();

    // pass B: phys = 272*a0 + 17*j + c0
    const int pa = 272 * (t >> 4) + (t & 15);
#pragma unroll
    for (int j = 0; j < 16; ++j) v[j] = s[pa + 17 * j];
    fwht16(v);
#pragma unroll
    for (int j = 0; j < 16; ++j) s[pa + 17 * j] = v[j];
    __syncthreads();

    // pass A: phys = 272*j + 17*b0 + c0
    const int pb = 17 * (t >> 4) + (t & 15);
#pragma unroll
    for (int j = 0; j < 16; ++j) v[j] = s[272 * j + pb];
    fwht16(v);

    const float sc = wscale[0] * 0.015625f;
    float* orow = OUT + (size_t)row * OUTF;
#pragma unroll
    for (int j = 0; j < 16; ++j)
        orow[j * 256 + t] = v[j] * sc * SV[j * 256 + t];
}

// ---------------------------------------------------------------------------
extern "C" void kernel_launch(void* const* d_in, const int* in_sizes, int n_in,
                              void* d_out, int out_size, void* d_ws, size_t ws_size,
                              hipStream_t stream) {
    const float* input  = (const float*)d_in[0];   // (2048, 4096) f32
    const int*   Qidxs  = (const int*)d_in[1];     // (4096, 512) i32
    const float* SU     = (const float*)d_in[2];   // (4096,) f32
    const float* SV     = (const float*)d_in[3];   // (4096,) f32
    const float* Wscale = (const float*)d_in[4];   // (1,) f32
    const void*  grid   = (const void*)d_in[9];    // (256, 8) grid_abs

    i8*    W  = (i8*)d_ws;                                         // 16 MB
    i8*    Y  = (i8*)((char*)d_ws + (size_t)16 * 1024 * 1024);     //  8 MB
    us16*  Z0 = (us16*)((char*)d_ws + (size_t)24 * 1024 * 1024);   // 16 MB
    us16*  Z1 = (us16*)((char*)d_ws + (size_t)40 * 1024 * 1024);   // 16 MB
    float* ZS = (float*)((char*)d_ws + (size_t)56 * 1024 * 1024);  //  8 KB

    hipLaunchKernelGGL(k_pre, dim3(TOKENS + (OUTF * 512) / 256), dim3(256), 0, stream,
                       input, SU, Y, ZS, Qidxs, grid, W);
    hipLaunchKernelGGL(k_gemm, dim3(512), dim3(512), 0, stream,
                       Y, W, ZS, Z0, Z1);
    hipLaunchKernelGGL(k_out, dim3(TOKENS), dim3(256), 0, stream,
                       Z0, Z1, (float*)d_out, SV, Wscale);
}

// Round 14
// 73.678 us; speedup vs baseline: 3.1482x; 1.2746x over previous
//
#include <hip/hip_runtime.h>

typedef short s16;
typedef unsigned short us16;
typedef signed char i8;
typedef __attribute__((ext_vector_type(8))) short s16x8;
typedef __attribute__((ext_vector_type(8))) unsigned short u16x8;
typedef __attribute__((ext_vector_type(8))) signed char i8x8;
typedef __attribute__((ext_vector_type(16))) signed char i8x16;
typedef __attribute__((ext_vector_type(4))) int i32x4;

#define TOKENS 2048
#define INF    4096
#define OUTF   4096
#define GK     4096

__device__ __forceinline__ us16 f2bf(float f) {
    union { float f; unsigned u; } v; v.f = f;
    unsigned r = v.u + 0x7FFFu + ((v.u >> 16) & 1u);
    return (us16)(r >> 16);
}
__device__ __forceinline__ float bf2f(us16 u) {
    unsigned x = ((unsigned)u) << 16;
    float f; __builtin_memcpy(&f, &x, 4);
    return f;
}

__device__ __forceinline__ void fwht16(float v[16]) {
#pragma unroll
    for (int s = 1; s < 16; s <<= 1)
#pragma unroll
        for (int j = 0; j < 16; ++j)
            if (!(j & s)) {
                float a = v[j], b = v[j + s];
                v[j]     = a + b;
                v[j + s] = a - b;
            }
}

// ---------------------------------------------------------------------------
// Kernel 1: blocks [0,2048): y_i8 = quant(FWHT(x*SU)), per-row scale -> ZS
//           blocks [2048,3072): decompress E8P -> W_i8 = W*4 (EXACT in i8),
//           8 chunks of 256 codes per block (LUT built ONCE per block).
// ZS[row] = vmax * (1/64) / (127*4)  so  z = acc_i32 * ZS[row]
// ---------------------------------------------------------------------------
__global__ __launch_bounds__(256) void k_pre(const float* __restrict__ X,
                                             const float* __restrict__ SU,
                                             i8* __restrict__ Y,
                                             float* __restrict__ ZS,
                                             const int* __restrict__ Q,
                                             const void* __restrict__ gridraw,
                                             i8* __restrict__ W) {
    __shared__ float s[4096 + 272];
    const int tid = threadIdx.x;

    if (blockIdx.x < TOKENS) {
        const int row = blockIdx.x;
        const int hi = tid >> 4, lo = tid & 15;
        float v[16];
        const float* xr = X + (size_t)row * INF;

#pragma unroll
        for (int j = 0; j < 16; ++j) v[j] = xr[j * 256 + tid] * SU[j * 256 + tid];
        fwht16(v);
#pragma unroll
        for (int j = 0; j < 16; ++j) s[272 * j + 17 * hi + lo] = v[j];
        __syncthreads();

#pragma unroll
        for (int j = 0; j < 16; ++j) v[j] = s[272 * hi + 17 * j + lo];
        fwht16(v);
#pragma unroll
        for (int j = 0; j < 16; ++j) s[272 * hi + 17 * j + lo] = v[j];
        __syncthreads();

        const int base = 272 * hi + 17 * lo;
#pragma unroll
        for (int j = 0; j < 16; ++j) v[j] = s[base + j];
        fwht16(v);

        // per-row absmax reduce (s[] reads are done; reuse s[0..255])
        float m16 = 0.f;
#pragma unroll
        for (int j = 0; j < 16; ++j) m16 = fmaxf(m16, fabsf(v[j]));
        __syncthreads();
        s[tid] = m16;
        __syncthreads();
#pragma unroll
        for (int off = 128; off > 0; off >>= 1) {
            if (tid < off) s[tid] = fmaxf(s[tid], s[tid + off]);
            __syncthreads();
        }
        const float vmax = fmaxf(s[0], 1e-30f);
        const float qs = 127.0f / vmax;

        i8x16 o;
#pragma unroll
        for (int j = 0; j < 16; ++j) o[j] = (i8)__float2int_rn(v[j] * qs);
        *reinterpret_cast<i8x16*>(Y + (size_t)row * INF + tid * 16) = o;
        if (tid == 0) ZS[row] = vmax * (0.015625f / 508.0f);  // /64 /(127*4)
    } else {
        float (*gT)[256] = (float(*)[256])s;
        int* gOdd = (int*)(s + 2048);

        const unsigned short* gu = (const unsigned short*)gridraw;
        const float*          gf = (const float*)gridraw;
        const unsigned short  p0 = gu[0];

        float sum = 0.f;
#pragma unroll
        for (int j = 0; j < 8; ++j) {
            float v;
            if (p0 == 0x3800) {                       // float16
                unsigned short u = gu[tid * 8 + j];
                _Float16 hv; __builtin_memcpy(&hv, &u, 2);
                v = (float)hv;
            } else if (p0 == 0x3F00) {                // bfloat16
                v = bf2f(gu[tid * 8 + j]);
            } else {                                  // float32
                v = gf[tid * 8 + j];
            }
            gT[j][tid] = v;
            sum += v;
        }
        gOdd[tid] = ((int)(sum + 0.5f)) & 1;
        __syncthreads();

        // 8 chunks of 256 codes per block; LUT built once above
        const int chunk0 = (blockIdx.x - TOKENS) * 8;
#pragma unroll
        for (int c = 0; c < 8; ++c) {
            const int code = (chunk0 + c) * 256 + tid;
            const int q        = Q[code];
            const int absIdx   = (q >> 8) & 255;
            const int signBits = (q >> 1) & 127;
            const float shift  = (q & 1) ? 1.0f : -1.0f;    // 0.25 * 4
            const int neg0 = (__popc(signBits) ^ gOdd[absIdx]) & 1;

            i8x8 o;
            o[0] = (i8)__float2int_rn(gT[0][absIdx] * 4.0f * (1.0f - 2.0f * (float)neg0) + shift);
#pragma unroll
            for (int i = 1; i < 8; ++i) {
                float sg = 1.0f - 2.0f * (float)((signBits >> (i - 1)) & 1);
                o[i] = (i8)__float2int_rn(gT[i][absIdx] * 4.0f * sg + shift);
            }
            *reinterpret_cast<i8x8*>(W + (size_t)code * 8) = o;
        }
    }
}

// ---------------------------------------------------------------------------
// Kernel 2: GEMM  z[t][j] = sum_k yq[t][k] * wq[j][k]  (NT, K-major, int8)
// 128x256 tile, BK=64 i8, 8 waves (2Mx4N), wave tile 64x64, KSPLIT=2.
// mfma_i32_16x16x64_i8. T4 counted-vmcnt loop (raw s_barrier, NEVER vmcnt(0)
// mid-loop): {12 ds_read -> lgkmcnt(0) -> s_barrier(read-rendezvous) ->
// STAGE(t+2,cur) -> 16 MFMA -> vmcnt(3) -> s_barrier}. vmcnt(3) retires
// exactly tile t+1's 3 loads; t+2's 3 stay in flight across the barrier.
// 16B-chunk XOR swizzle c ^= (row>>1)&3 on write source and read sides.
// ---------------------------------------------------------------------------
#define BM 128
#define BN 256
#define BK 64   // i8 elements = 64 bytes per row = 4 x 16B chunks

__global__ __launch_bounds__(512, 4) void k_gemm(const i8* __restrict__ A,
                                                 const i8* __restrict__ B,
                                                 const float* __restrict__ ZS,
                                                 us16* __restrict__ Z0,
                                                 us16* __restrict__ Z1) {
    __shared__ __align__(16) i8 lA[2][BM * BK];   // 2 x 8 KiB
    __shared__ __align__(16) i8 lB[2][BN * BK];   // 2 x 16 KiB
    const int tid  = threadIdx.x;
    const int lane = tid & 63;
    const int w    = tid >> 6;
    const int wr   = w >> 2, wc = w & 3;
    const int laneRow = lane & 15, laneK = lane >> 4;   // laneK 0..3

    // bijective XCD swizzle over nwg = 512
    const int bid = blockIdx.x;
    const int swz = (bid & 7) * 64 + (bid >> 3);
    const int ks  = swz >> 8;           // 0..1
    const int rem = swz & 255;
    const int mT  = rem >> 4;           // 0..15
    const int nT  = rem & 15;           // 0..15
    const int KT  = (GK / 2) / BK;      // 32
    const size_t kbase = (size_t)ks * (GK / 2);

    us16* __restrict__ Z = (ks == 1) ? Z1 : Z0;

    // staging: A 512 chunks (1/thread), B 1024 chunks (2/thread), 16B each
    size_t aOff;
    {
        int rr = tid >> 2, cc = tid & 3;
        int sc = cc ^ ((rr >> 1) & 3);
        aOff = (size_t)(mT * BM + rr) * GK + kbase + sc * 16;
    }
    const int ldsOffA = w * 64 * 16;        // wave-uniform bytes
    size_t bOff[2];
    int ldsOffB[2];
#pragma unroll
    for (int j = 0; j < 2; ++j) {
        int ch = j * 512 + tid;
        int rr = ch >> 2, cc = ch & 3;
        int sc = cc ^ ((rr >> 1) & 3);
        bOff[j] = (size_t)(nT * BN + rr) * GK + kbase + sc * 16;
        ldsOffB[j] = (j * 512 + w * 64) * 16;
    }

    // fragment read bases (bytes): row r -> r*64 + (laneK ^ ((r>>1)&3))*16
    int aB[4], aX[4], bB[4], bX[4];
#pragma unroll
    for (int mi = 0; mi < 4; ++mi) {
        int r = wr * 64 + mi * 16 + laneRow;
        aB[mi] = r * 64; aX[mi] = (r >> 1) & 3;
    }
#pragma unroll
    for (int nj = 0; nj < 4; ++nj) {
        int r = wc * 64 + nj * 16 + laneRow;
        bB[nj] = r * 64; bX[nj] = (r >> 1) & 3;
    }

    i32x4 acc[4][4] = {};

#define STAGE(t, buf) do { const size_t _ko = (size_t)(t) * BK; \
    __builtin_amdgcn_global_load_lds( \
        (const __attribute__((address_space(1))) void*)(A + aOff + _ko), \
        (__attribute__((address_space(3))) void*)(&lA[buf][0] + ldsOffA), 16, 0, 0); \
    _Pragma("unroll") \
    for (int j = 0; j < 2; ++j) \
        __builtin_amdgcn_global_load_lds( \
            (const __attribute__((address_space(1))) void*)(B + bOff[j] + _ko), \
            (__attribute__((address_space(3))) void*)(&lB[buf][0] + ldsOffB[j]), 16, 0, 0); \
    } while (0)

    // prologue: stage tiles 0,1; counted wait -> tile 0 landed, tile 1 in flight
    STAGE(0, 0);
    STAGE(1, 1);
    asm volatile("s_waitcnt vmcnt(3)" ::: "memory");
    __builtin_amdgcn_sched_barrier(0);
    __builtin_amdgcn_s_barrier();

    int cur = 0;
    for (int t = 0; t < KT; ++t) {
        const i8* pA = &lA[cur][0];
        const i8* pB = &lB[cur][0];

        i32x4 af[4], bf[4];
#pragma unroll
        for (int mi = 0; mi < 4; ++mi)
            af[mi] = *reinterpret_cast<const i32x4*>(pA + aB[mi] + (laneK ^ aX[mi]) * 16);
#pragma unroll
        for (int nj = 0; nj < 4; ++nj)
            bf[nj] = *reinterpret_cast<const i32x4*>(pB + bB[nj] + (laneK ^ bX[nj]) * 16);

        // own reads in regs; rendezvous -> ALL waves' reads of buf[cur] done
        asm volatile("s_waitcnt lgkmcnt(0)" ::: "memory");
        __builtin_amdgcn_sched_barrier(0);
        __builtin_amdgcn_s_barrier();

        // stage t+2 into the just-freed buffer (DMA, doesn't touch regs)
        if (t + 2 < KT) { STAGE(t + 2, cur); }

#pragma unroll
        for (int mi = 0; mi < 4; ++mi)
#pragma unroll
            for (int nj = 0; nj < 4; ++nj)
                acc[mi][nj] = __builtin_amdgcn_mfma_i32_16x16x64_i8(
                    af[mi], bf[nj], acc[mi][nj], 0, 0, 0);

        // boundary: counted — tile t+1's 3 loads retired, t+2's stay in flight
        if (t + 1 < KT) {
            if (t + 2 < KT) {
                asm volatile("s_waitcnt vmcnt(3)" ::: "memory");
            } else {
                asm volatile("s_waitcnt vmcnt(0)" ::: "memory");
            }
            __builtin_amdgcn_sched_barrier(0);
            __builtin_amdgcn_s_barrier();
        }
        cur ^= 1;
    }
#undef STAGE

    // C/D layout: col = lane&15, row = (lane>>4)*4 + reg
    const int colB = nT * BN + wc * 64 + laneRow;
    const int rowB = mT * BM + wr * 64 + laneK * 4;
#pragma unroll
    for (int mi = 0; mi < 4; ++mi) {
#pragma unroll
        for (int rg = 0; rg < 4; ++rg) {
            const int row = rowB + mi * 16 + rg;
            const float zs = ZS[row];
#pragma unroll
            for (int nj = 0; nj < 4; ++nj)
                Z[(size_t)row * OUTF + colB + nj * 16]
                    = f2bf((float)acc[mi][nj][rg] * zs);
        }
    }
}

// ---------------------------------------------------------------------------
// Kernel 3: OUT = FWHT(bf16 Z0 + bf16 Z1) * Wscale/64 * SV  (digit-reordered)
// ---------------------------------------------------------------------------
__global__ __launch_bounds__(256) void k_out(const us16* __restrict__ Z0,
                                             const us16* __restrict__ Z1,
                                             float* __restrict__ OUT,
                                             const float* __restrict__ SV,
                                             const float* __restrict__ wscale) {
    __shared__ float s[4096 + 272];
    const int row = blockIdx.x, t = threadIdx.x;
    float v[16];
    const us16* zr0 = Z0 + (size_t)row * OUTF;
    const us16* zr1 = Z1 + (size_t)row * OUTF;

    // pass C (low digit): contiguous 32B loads
    {
        u16x8 a0 = reinterpret_cast<const u16x8*>(zr0 + t * 16)[0];
        u16x8 a1 = reinterpret_cast<const u16x8*>(zr0 + t * 16)[1];
        u16x8 b0 = reinterpret_cast<const u16x8*>(zr1 + t * 16)[0];
        u16x8 b1 = reinterpret_cast<const u16x8*>(zr1 + t * 16)[1];
#pragma unroll
        for (int j = 0; j < 8; ++j) {
            v[j]     = bf2f(a0[j]) + bf2f(b0[j]);
            v[j + 8] = bf2f(a1[j]) + bf2f(b1[j]);
        }
    }
    fwht16(v);
#pragma unroll
    for (int j = 0; j < 16; ++j) s[17 * t + j] = v[j];
    __syncthreads();

    // pass B: phys = 272*a0 + 17*j + c0
    const int pa = 272 * (t >> 4) + (t & 15);
#pragma unroll
    for (int j = 0; j < 16; ++j) v[j] = s[pa + 17 * j];
    fwht16(v);
#pragma unroll
    for (int j = 0; j < 16; ++j) s[pa + 17 * j] = v[j];
    __syncthreads();

    // pass A: phys = 272*j + 17*b0 + c0
    const int pb = 17 * (t >> 4) + (t & 15);
#pragma unroll
    for (int j = 0; j < 16; ++j) v[j] = s[272 * j + pb];
    fwht16(v);

    const float sc = wscale[0] * 0.015625f;
    float* orow = OUT + (size_t)row * OUTF;
#pragma unroll
    for (int j = 0; j < 16; ++j)
        orow[j * 256 + t] = v[j] * sc * SV[j * 256 + t];
}

// ---------------------------------------------------------------------------
extern "C" void kernel_launch(void* const* d_in, const int* in_sizes, int n_in,
                              void* d_out, int out_size, void* d_ws, size_t ws_size,
                              hipStream_t stream) {
    const float* input  = (const float*)d_in[0];   // (2048, 4096) f32
    const int*   Qidxs  = (const int*)d_in[1];     // (4096, 512) i32
    const float* SU     = (const float*)d_in[2];   // (4096,) f32
    const float* SV     = (const float*)d_in[3];   // (4096,) f32
    const float* Wscale = (const float*)d_in[4];   // (1,) f32
    const void*  grid   = (const void*)d_in[9];    // (256, 8) grid_abs

    i8*    W  = (i8*)d_ws;                                         // 16 MB
    i8*    Y  = (i8*)((char*)d_ws + (size_t)16 * 1024 * 1024);     //  8 MB
    us16*  Z0 = (us16*)((char*)d_ws + (size_t)24 * 1024 * 1024);   // 16 MB
    us16*  Z1 = (us16*)((char*)d_ws + (size_t)40 * 1024 * 1024);   // 16 MB
    float* ZS = (float*)((char*)d_ws + (size_t)56 * 1024 * 1024);  //  8 KB

    hipLaunchKernelGGL(k_pre, dim3(TOKENS + 1024), dim3(256), 0, stream,
                       input, SU, Y, ZS, Qidxs, grid, W);
    hipLaunchKernelGGL(k_gemm, dim3(512), dim3(512), 0, stream,
                       Y, W, ZS, Z0, Z1);
    hipLaunchKernelGGL(k_out, dim3(TOKENS), dim3(256), 0, stream,
                       Z0, Z1, (float*)d_out, SV, Wscale);
}